// Round 3
// baseline (8689.235 us; speedup 1.0000x reference)
//
#include <hip/hip_runtime.h>
#include <math.h>

#define NB 8
#define NC 64
#define NH 256
#define NW 256
#define NM 40      // 2*MODES1 (rows 0..19 and 236..255)
#define NKX 20     // MODES2
#define NL 4

// ---- per-chunk workspace pieces (in floats), cb = images per chunk ----
#define PERCB_FLOATS ((size_t)(2*4194304 + 655360 + 2*102400))   // 9,248,768
#define FIXED_FLOATS ((size_t)(6553600 + 10240 + 20480 + 147456 + 256)) // 6,732,032

static __device__ __forceinline__ float gelu_f(float v) {
  return 0.5f * v * (1.f + erff(v * 0.70710678118654752f));
}

// ---------------------------------------------------------------------------
__global__ __launch_bounds__(256) void k_tables(float2* __restrict__ Tx,
                                                float2* __restrict__ Ty) {
  int t = blockIdx.x * 256 + threadIdx.x;
  const float w = (float)(2.0 * 3.14159265358979323846 / 256.0);
  if (t < NKX * 256) {
    int kx = t >> 8, x = t & 255;
    float th = (float)((kx * x) & 255) * w;
    Tx[t] = make_float2(cosf(th), sinf(th));
  }
  int u = t - NKX * 256;
  if (u >= 0 && u < NM * 256) {
    int m = u >> 8, y = u & 255;
    int ky = (m < 20) ? m : (m + 216);
    float th = (float)((ky * y) & 255) * w;
    Ty[u] = make_float2(cosf(th), sinf(th));
  }
}

// ---------------------------------------------------------------------------
__global__ __launch_bounds__(256) void k_wc(const float* __restrict__ ch,
                                            const float* __restrict__ cw,
                                            const float* __restrict__ pw,
                                            const float* __restrict__ chb,
                                            const float* __restrict__ cwb,
                                            const float* __restrict__ pwb,
                                            float* __restrict__ wc,
                                            float* __restrict__ bc) {
  int t = blockIdx.x * 256 + threadIdx.x;
  if (t < NL * NC * NC * 9) {
    int tap = t % 9;
    int io  = t / 9;
    int o   = io % 64;
    int i   = (io / 64) % 64;
    int l   = io / 4096;
    int src = ((l * 64 + o) * 64 + i) * 9 + tap;
    float v = ch[src] + cw[src];
    if (tap == 4) v += pw[(l * 64 + o) * 64 + i];
    wc[t] = v;
  }
  if (t < NL * NC) bc[t] = chb[t] + cwb[t] + pwb[t];
}

// ---------------------------------------------------------------------------
__global__ __launch_bounds__(256) void k_fc0(const float* __restrict__ x,
                                             const float* __restrict__ w,
                                             const float* __restrict__ b,
                                             float* __restrict__ h, int b0) {
  int t = blockIdx.x * 256 + threadIdx.x;
  int xw = t & 255;
  int y  = (t >> 8) & 255;
  int c  = (t >> 16) & 63;
  int bb = t >> 22;
  const float* xp = x + (((size_t)(b0 + bb) * 256 + y) * 256 + xw) * 3;
  h[t] = xp[0] * w[c] + xp[1] * w[64 + c] + xp[2] * w[128 + c] + b[c];
}

// ---------------------------------------------------------------------------
// Partial DFT along x. LDS row stride 260 floats (16B-aligned, breaks 257-odd).
// Compute: 240 threads = (row-pair, kx); float4/b128 vector reads, 32 FMA / 4 loads.
__global__ __launch_bounds__(256) void k_fwdx(const float* __restrict__ h,
                                              const float2* __restrict__ Tx,
                                              float2* __restrict__ Fx, int nrows) {
  __shared__ float sm[24 * 260];
  int row0 = blockIdx.x * 24;
  for (int t = threadIdx.x; t < 24 * 256; t += 256) {
    int r = t >> 8, xx = t & 255;
    int row = row0 + r;
    sm[r * 260 + xx] = (row < nrows) ? h[(size_t)row * 256 + xx] : 0.f;
  }
  __syncthreads();
  int t = threadIdx.x;
  if (t < 240) {
    int pair = t / 20, kx = t % 20;
    int r = pair * 2;
    const float4* s0 = (const float4*)(sm + r * 260);
    const float4* s1 = (const float4*)(sm + (r + 1) * 260);
    const float4* tw = (const float4*)(Tx + kx * 256);   // (c0,s0,c1,s1) per elt
    float re0 = 0.f, im0 = 0.f, re1 = 0.f, im1 = 0.f;
    #pragma unroll 4
    for (int q = 0; q < 64; ++q) {
      float4 a  = s0[q];
      float4 b  = s1[q];
      float4 t0 = tw[2 * q];
      float4 t1 = tw[2 * q + 1];
      re0 += a.x * t0.x + a.y * t0.z + a.z * t1.x + a.w * t1.z;
      im0 -= a.x * t0.y + a.y * t0.w + a.z * t1.y + a.w * t1.w;
      re1 += b.x * t0.x + b.y * t0.z + b.z * t1.x + b.w * t1.z;
      im1 -= b.x * t0.y + b.y * t0.w + b.z * t1.y + b.w * t1.w;
    }
    int g0 = row0 + r, g1 = row0 + r + 1;
    if (g0 < nrows) Fx[(size_t)g0 * 20 + kx] = make_float2(re0, im0);
    if (g1 < nrows) Fx[(size_t)g1 * 20 + kx] = make_float2(re1, im1);
  }
}

// ---------------------------------------------------------------------------
__global__ __launch_bounds__(256) void k_fwdy(const float2* __restrict__ Fx,
                                              const float2* __restrict__ Ty,
                                              float2* __restrict__ Fxy) {
  int t  = blockIdx.x * 256 + threadIdx.x;   // cb*64*40*20
  int kx = t % 20;
  int m  = (t / 20) % 40;
  int bc = t / 800;
  const float2* fp = Fx + (size_t)bc * NH * 20 + kx;
  const float2* tp = Ty + m * 256;
  float re = 0.f, im = 0.f;
  #pragma unroll 4
  for (int y = 0; y < 256; ++y) {
    float2 f = fp[y * 20];
    float2 w = tp[y];
    re += f.x * w.x + f.y * w.y;
    im += f.y * w.x - f.x * w.y;
  }
  Fxy[t] = make_float2(re * (1.f / 256.f), im * (1.f / 256.f));
}

// ---------------------------------------------------------------------------
__global__ __launch_bounds__(256) void k_wT(const float* __restrict__ w1,
                                            const float* __restrict__ w2,
                                            float2* __restrict__ wT, int l) {
  __shared__ float2 tile[32][33];
  int mk0 = blockIdx.x * 32;   // 25 blocks
  int io0 = blockIdx.y * 32;   // 128 blocks
  int tx = threadIdx.x & 31, ty0 = threadIdx.x >> 5;
  #pragma unroll
  for (int s = 0; s < 4; ++s) {
    int ty = ty0 * 4 + s;
    int mk = mk0 + tx, io = io0 + ty;
    int m = mk / 20, kx = mk % 20;
    const float* src = (m < 20) ? w1 : w2;
    int mm = (m < 20) ? m : (m - 20);
    size_t idx = ((((size_t)l * 4096 + io) * 20 + mm) * 20 + kx) * 2;
    tile[ty][tx] = make_float2(src[idx], src[idx + 1]);
  }
  __syncthreads();
  #pragma unroll
  for (int s = 0; s < 4; ++s) {
    int ty = ty0 * 4 + s;
    wT[(size_t)(mk0 + ty) * 4096 + (io0 + tx)] = tile[tx][ty];
  }
}

// ---------------------------------------------------------------------------
__global__ __launch_bounds__(256) void k_mix(const float2* __restrict__ Fxy,
                                             const float2* __restrict__ wT,
                                             float2* __restrict__ G, int nrows) {
  __shared__ float2 sf[512];
  int mk = blockIdx.x;
  for (int t = threadIdx.x; t < nrows; t += 256) sf[t] = Fxy[(size_t)t * 800 + mk];
  __syncthreads();
  const float2* wp = wT + (size_t)mk * 4096;
  for (int t = threadIdx.x; t < nrows; t += 256) {
    int b = t >> 6, o = t & 63;
    const float2* fb = sf + b * 64;
    float re = 0.f, im = 0.f;
    #pragma unroll 8
    for (int i = 0; i < 64; ++i) {
      float2 f = fb[i];
      float2 w = wp[i * 64 + o];
      re += f.x * w.x - f.y * w.y;
      im += f.x * w.y + f.y * w.x;
    }
    G[(size_t)(b * 64 + o) * 800 + mk] = make_float2(re, im);
  }
}

// ---------------------------------------------------------------------------
__global__ __launch_bounds__(256) void k_invy(const float2* __restrict__ G,
                                              const float2* __restrict__ Ty,
                                              float2* __restrict__ Gy) {
  int t  = blockIdx.x * 256 + threadIdx.x;   // cb*64*256*20
  int kx = t % 20;
  int y  = (t / 20) & 255;
  int bc = t / 5120;
  const float2* gp = G + (size_t)bc * 800 + kx;
  float re = 0.f, im = 0.f;
  #pragma unroll 4
  for (int m = 0; m < 40; ++m) {
    float2 g = gp[m * 20];
    float2 w = Ty[m * 256 + y];
    re += g.x * w.x - g.y * w.y;
    im += g.x * w.y + g.y * w.x;
  }
  Gy[t] = make_float2(re, im);
}

// ---------------------------------------------------------------------------
// Fused 3x3 conv + inverse-x DFT + gelu.
// __launch_bounds__(256,4): cap VGPR at 128 so acc[64] stays in ArchVGPRs
// (default cap of 64 forced acc into AGPRs -> 3 instr per FMA, 900us vs 250us floor).
__global__ __launch_bounds__(256, 4) void k_conv(const float* __restrict__ hin,
                                                 const float* __restrict__ wc,
                                                 const float* __restrict__ bcb,
                                                 const float2* __restrict__ Gy,
                                                 const float2* __restrict__ Tx,
                                                 float* __restrict__ hout,
                                                 int dogelu) {
  __shared__ float sm[16 * 340];          // 16 in-ch x 10 rows x 34 cols
  __shared__ float2 smTx[19 * 32];        // kx=1..19 twiddles for this x-tile
  int bidx = blockIdx.x;
  int x0 = (bidx & 7) << 5;
  int y0 = ((bidx >> 3) & 31) << 3;
  int bb = bidx >> 8;
  int px = threadIdx.x & 31, py = threadIdx.x >> 5;
  int y = y0 + py, x = x0 + px;

  for (int t = threadIdx.x; t < 19 * 32; t += 256)
    smTx[t] = Tx[(1 + (t >> 5)) * 256 + x0 + (t & 31)];

  float acc[64];
  #pragma unroll
  for (int o = 0; o < 64; ++o) acc[o] = bcb[o];

  for (int ci = 0; ci < 64; ci += 16) {
    __syncthreads();
    for (int t = threadIdx.x; t < 16 * 340; t += 256) {
      int i = t / 340, rem = t % 340;
      int r = rem / 34, cc = rem % 34;
      int gy = y0 - 1 + r, gx = x0 - 1 + cc;
      float v = 0.f;
      if (gy >= 0 && gy < NH && gx >= 0 && gx < NW)
        v = hin[(((size_t)bb * NC + ci + i) * NH + gy) * NW + gx];
      sm[t] = v;
    }
    __syncthreads();
    for (int i = 0; i < 16; ++i) {
      int base = i * 340 + py * 34 + px;
      float v00 = sm[base + 0],  v01 = sm[base + 1],  v02 = sm[base + 2];
      float v10 = sm[base + 34], v11 = sm[base + 35], v12 = sm[base + 36];
      float v20 = sm[base + 68], v21 = sm[base + 69], v22 = sm[base + 70];
      const float* wp = wc + (ci + i) * 576;   // uniform -> scalar loads
      #pragma unroll
      for (int o = 0; o < 64; ++o) {
        const float* wo = wp + o * 9;
        acc[o] += wo[0] * v00 + wo[1] * v01 + wo[2] * v02
                + wo[3] * v10 + wo[4] * v11 + wo[5] * v12
                + wo[6] * v20 + wo[7] * v21 + wo[8] * v22;
      }
    }
  }

  const float scale = 1.f / 256.f;
  #pragma unroll
  for (int o = 0; o < 64; ++o) {
    const float4* gp = (const float4*)(Gy + ((size_t)(bb * NC + o) * NH + y) * NKX);
    float4 g0 = gp[0];
    float2 t1 = smTx[px];
    float s = g0.x + 2.f * (g0.z * t1.x - g0.w * t1.y);
    #pragma unroll
    for (int p = 1; p < 10; ++p) {
      float4 g  = gp[p];
      float2 ta = smTx[(2 * p - 1) * 32 + px];
      float2 tb = smTx[(2 * p) * 32 + px];
      s += 2.f * (g.x * ta.x - g.y * ta.y) + 2.f * (g.z * tb.x - g.w * tb.y);
    }
    float v = acc[o] + s * scale;
    if (dogelu) v = gelu_f(v);
    hout[((size_t)(bb * NC + o) * NH + y) * NW + x] = v;
  }
}

// ---------------------------------------------------------------------------
// Head. Same VGPR-cap fix: hv[64] must stay in ArchVGPRs.
__global__ __launch_bounds__(256, 4) void k_head(const float* __restrict__ h,
                                                 const float* __restrict__ w1,
                                                 const float* __restrict__ b1,
                                                 const float* __restrict__ w2,
                                                 const float* __restrict__ b2,
                                                 float* __restrict__ out, int b0) {
  int t  = blockIdx.x * 256 + threadIdx.x;  // cb*H*W
  int xw = t & 255;
  int y  = (t >> 8) & 255;
  int bb = t >> 16;
  float hv[64];
  const float* hp = h + (size_t)bb * NC * NH * NW + y * 256 + xw;
  #pragma unroll
  for (int c = 0; c < 64; ++c) hv[c] = hp[(size_t)c * NH * NW];
  float o = b2[0];
  for (int j = 0; j < 128; ++j) {
    float s = b1[j];
    #pragma unroll
    for (int c = 0; c < 64; ++c) s += hv[c] * w1[c * 128 + j];
    s = gelu_f(s);
    o += s * w2[j];
  }
  out[(size_t)(b0 << 16) + t] = o;
}

// ---------------------------------------------------------------------------
extern "C" void kernel_launch(void* const* d_in, const int* in_sizes, int n_in,
                              void* d_out, int out_size, void* d_ws, size_t ws_size,
                              hipStream_t stream) {
  const float* x    = (const float*)d_in[0];
  const float* fc0w = (const float*)d_in[1];
  const float* fc0b = (const float*)d_in[2];
  const float* w1   = (const float*)d_in[3];
  const float* w2   = (const float*)d_in[4];
  const float* chw  = (const float*)d_in[5];
  const float* chb  = (const float*)d_in[6];
  const float* cww  = (const float*)d_in[7];
  const float* cwb  = (const float*)d_in[8];
  const float* pww  = (const float*)d_in[9];
  const float* pwb  = (const float*)d_in[10];
  const float* fc1w = (const float*)d_in[11];
  const float* fc1b = (const float*)d_in[12];
  const float* fc2w = (const float*)d_in[13];
  const float* fc2b = (const float*)d_in[14];

  int cb = 1;
  for (int cand = 8; cand >= 1; cand >>= 1) {
    size_t need = (PERCB_FLOATS * (size_t)cand + FIXED_FLOATS) * sizeof(float);
    if (ws_size >= need) { cb = cand; break; }
  }

  const size_t szH  = (size_t)cb * 4194304;   // floats
  const size_t szFX = (size_t)cb * 655360;
  const size_t szG  = (size_t)cb * 102400;

  float*  ws  = (float*)d_ws;
  float*  h   = ws;
  float*  h2  = h + szH;
  float2* Fx  = (float2*)(h2 + szH);
  float2* Fxy = (float2*)((float*)Fx + szFX);
  float2* G   = (float2*)((float*)Fxy + szG);
  float2* wT  = (float2*)((float*)G + szG);
  float2* Tx  = (float2*)((float*)wT + 6553600);
  float2* Ty  = (float2*)((float*)Tx + 10240);
  float*  wcb = (float*)Ty + 20480;
  float*  bcb = wcb + 147456;
  float2* Gy  = Fx;   // Fx dead after k_fwdy; reuse as Gy

  k_tables<<<60, 256, 0, stream>>>(Tx, Ty);
  k_wc<<<(NL * NC * NC * 9 + 255) / 256, 256, 0, stream>>>(chw, cww, pww, chb, cwb, pwb, wcb, bcb);

  for (int b0 = 0; b0 < NB; b0 += cb) {
    k_fc0<<<cb * 16384, 256, 0, stream>>>(x, fc0w, fc0b, h, b0);
    float* cur = h;
    float* nxt = h2;
    int nrows = cb * NC * NH;
    for (int l = 0; l < NL; ++l) {
      k_fwdx<<<(nrows + 23) / 24, 256, 0, stream>>>(cur, Tx, Fx, nrows);
      k_fwdy<<<cb * 200, 256, 0, stream>>>(Fx, Ty, Fxy);
      k_wT<<<dim3(25, 128), 256, 0, stream>>>(w1, w2, wT, l);
      k_mix<<<NM * NKX, 256, 0, stream>>>(Fxy, wT, G, cb * 64);
      k_invy<<<cb * 1280, 256, 0, stream>>>(G, Ty, Gy);
      k_conv<<<cb * 256, 256, 0, stream>>>(cur, wcb + (size_t)l * 36864,
                                           bcb + (size_t)l * 64, Gy, Tx, nxt,
                                           (l < NL - 1) ? 1 : 0);
      float* tmp = cur; cur = nxt; nxt = tmp;
    }
    k_head<<<cb * 256, 256, 0, stream>>>(cur, fc1w, fc1b, fc2w, fc2b,
                                         (float*)d_out, b0);
  }
}

// Round 6
// 4930.171 us; speedup vs baseline: 1.7625x; 1.7625x over previous
//
#include <hip/hip_runtime.h>
#include <math.h>

#define NB 8
#define NC 64
#define NH 256
#define NW 256
#define NM 40      // 2*MODES1
#define NKX 20     // MODES2
#define NL 4

typedef _Float16 f16x8 __attribute__((ext_vector_type(8)));
typedef float    f32x4 __attribute__((ext_vector_type(4)));

// ---- workspace (floats) ----
#define PERCB_FLOATS ((size_t)(2*4194304 + 655360 + 2*102400))   // 9,248,768
#define FIXED_FLOATS ((size_t)(6553600 + 10240 + 20480 + 147456 + 256 + 155648))

static __device__ __forceinline__ float gelu_f(float v) {
  return 0.5f * v * (1.f + erff(v * 0.70710678118654752f));
}
static __device__ __forceinline__ unsigned pack2(_Float16 a, _Float16 b) {
  union { _Float16 h[2]; unsigned u; } x; x.h[0] = a; x.h[1] = b; return x.u;
}

// ---------------------------------------------------------------------------
__global__ __launch_bounds__(256) void k_tables(float2* __restrict__ Tx,
                                                float2* __restrict__ Ty) {
  int t = blockIdx.x * 256 + threadIdx.x;
  const float w = (float)(2.0 * 3.14159265358979323846 / 256.0);
  if (t < NKX * 256) {
    int kx = t >> 8, x = t & 255;
    float th = (float)((kx * x) & 255) * w;
    Tx[t] = make_float2(cosf(th), sinf(th));
  }
  int u = t - NKX * 256;
  if (u >= 0 && u < NM * 256) {
    int m = u >> 8, y = u & 255;
    int ky = (m < 20) ? m : (m + 216);
    float th = (float)((ky * y) & 255) * w;
    Ty[u] = make_float2(cosf(th), sinf(th));
  }
}

// ---------------------------------------------------------------------------
__global__ __launch_bounds__(256) void k_wc(const float* __restrict__ ch,
                                            const float* __restrict__ cw,
                                            const float* __restrict__ pw,
                                            const float* __restrict__ chb,
                                            const float* __restrict__ cwb,
                                            const float* __restrict__ pwb,
                                            float* __restrict__ wc,
                                            float* __restrict__ bc) {
  int t = blockIdx.x * 256 + threadIdx.x;
  if (t < NL * NC * NC * 9) {
    int tap = t % 9;
    int io  = t / 9;
    int o   = io % 64;
    int i   = (io / 64) % 64;
    int l   = io / 4096;
    int src = ((l * 64 + o) * 64 + i) * 9 + tap;
    float v = ch[src] + cw[src];
    if (tap == 4) v += pw[(l * 64 + o) * 64 + i];
    wc[t] = v;
  }
  if (t < NL * NC) bc[t] = chb[t] + cwb[t] + pwb[t];
}

// ---------------------------------------------------------------------------
// Pack conv weights into MFMA b-frag order, split into f16 hi/lo.
// b-frag: lane l, j: W[i = half*32 + (l>>4)*8 + j][o = nt*16 + (l&15)], tap.
// idx (f16x8 units) = ((l4*18 + chunk)*4 + nt)*64 + lane,  chunk = tap*2+half
__global__ __launch_bounds__(256) void k_wpack(const float* __restrict__ wc,
                                               _Float16* __restrict__ whi,
                                               _Float16* __restrict__ wlo) {
  int t = blockIdx.x * 256 + threadIdx.x;     // 4*18*4*64 = 18432
  int lane = t & 63;
  int nt   = (t >> 6) & 3;
  int chunk = (t >> 8) % 18;
  int l4   = t / 4608;
  int tap = chunk >> 1, half = chunk & 1;
  int o = nt * 16 + (lane & 15);
  _Float16 hi[8], lo[8];
  #pragma unroll
  for (int j = 0; j < 8; ++j) {
    int i = half * 32 + ((lane >> 4) << 3) + j;
    float v = wc[((l4 * 64 + i) * 64 + o) * 9 + tap];
    _Float16 h = (_Float16)v;
    hi[j] = h;
    lo[j] = (_Float16)(v - (float)h);
  }
  *(f16x8*)(whi + (size_t)t * 8) = *(f16x8*)hi;
  *(f16x8*)(wlo + (size_t)t * 8) = *(f16x8*)lo;
}

// ---------------------------------------------------------------------------
// Pack fc1 weights (64 x 128) into b-frag order (2 chunks x 8 nt).
__global__ __launch_bounds__(256) void k_hpack(const float* __restrict__ w1,
                                               _Float16* __restrict__ whi,
                                               _Float16* __restrict__ wlo) {
  int t = blockIdx.x * 256 + threadIdx.x;     // 2*8*64 = 1024
  int lane = t & 63;
  int nt   = (t >> 6) & 7;
  int chunk = t >> 9;
  int jo = nt * 16 + (lane & 15);
  _Float16 hi[8], lo[8];
  #pragma unroll
  for (int j = 0; j < 8; ++j) {
    int c = chunk * 32 + ((lane >> 4) << 3) + j;
    float v = w1[c * 128 + jo];
    _Float16 h = (_Float16)v;
    hi[j] = h;
    lo[j] = (_Float16)(v - (float)h);
  }
  *(f16x8*)(whi + (size_t)t * 8) = *(f16x8*)hi;
  *(f16x8*)(wlo + (size_t)t * 8) = *(f16x8*)lo;
}

// ---------------------------------------------------------------------------
// fc0 lift -> h in NHWC: h[px*64 + ch]
__global__ __launch_bounds__(256) void k_fc0(const float* __restrict__ x,
                                             const float* __restrict__ w,
                                             const float* __restrict__ b,
                                             float* __restrict__ h, int b0) {
  int t = blockIdx.x * 256 + threadIdx.x;    // cb*65536*64
  int ch = t & 63;
  int px = t >> 6;                           // chunk-local pixel
  const float* xp = x + ((size_t)b0 * 65536 + px) * 3;
  h[t] = xp[0] * w[ch] + xp[1] * w[64 + ch] + xp[2] * w[128 + ch] + b[ch];
}

// ---------------------------------------------------------------------------
// Forward x-DFT, NHWC input. Block = (bb, y); wave w owns kx in [5w, 5w+5);
// lane = channel. Coalesced channel-vector reads per x.
__global__ __launch_bounds__(256) void k_fwdx(const float* __restrict__ h,
                                              const float2* __restrict__ Tx,
                                              float2* __restrict__ Fx) {
  int bidx = blockIdx.x;
  int y  = bidx & 255;
  int bb = bidx >> 8;
  int w  = threadIdx.x >> 6;
  int ch = threadIdx.x & 63;
  const float* hp = h + ((size_t)bb * 65536 + y * 256) * 64 + ch;
  float ar[5] = {0,0,0,0,0}, ai[5] = {0,0,0,0,0};
  #pragma unroll 4
  for (int x = 0; x < 256; x += 2) {
    float v0 = hp[(size_t)x * 64];
    float v1 = hp[(size_t)(x + 1) * 64];
    #pragma unroll
    for (int q = 0; q < 5; ++q) {
      int kx = w * 5 + q;
      float4 t4 = *(const float4*)(Tx + kx * 256 + x);
      ar[q] += v0 * t4.x + v1 * t4.z;
      ai[q] -= v0 * t4.y + v1 * t4.w;
    }
  }
  float2* fp = Fx + ((size_t)(bb * 64 + ch) * 256 + y) * 20;
  #pragma unroll
  for (int q = 0; q < 5; ++q) fp[w * 5 + q] = make_float2(ar[q], ai[q]);
}

// ---------------------------------------------------------------------------
__global__ __launch_bounds__(256) void k_fwdy(const float2* __restrict__ Fx,
                                              const float2* __restrict__ Ty,
                                              float2* __restrict__ Fxy) {
  int t  = blockIdx.x * 256 + threadIdx.x;   // cb*64*40*20
  int kx = t % 20;
  int m  = (t / 20) % 40;
  int bc = t / 800;
  const float2* fp = Fx + (size_t)bc * NH * 20 + kx;
  const float2* tp = Ty + m * 256;
  float re = 0.f, im = 0.f;
  #pragma unroll 4
  for (int y = 0; y < 256; ++y) {
    float2 f = fp[y * 20];
    float2 w = tp[y];
    re += f.x * w.x + f.y * w.y;
    im += f.y * w.x - f.x * w.y;
  }
  Fxy[t] = make_float2(re * (1.f / 256.f), im * (1.f / 256.f));
}

// ---------------------------------------------------------------------------
__global__ __launch_bounds__(256) void k_wT(const float* __restrict__ w1,
                                            const float* __restrict__ w2,
                                            float2* __restrict__ wT, int l) {
  __shared__ float2 tile[32][33];
  int mk0 = blockIdx.x * 32;   // 25
  int io0 = blockIdx.y * 32;   // 128
  int tx = threadIdx.x & 31, ty0 = threadIdx.x >> 5;
  #pragma unroll
  for (int s = 0; s < 4; ++s) {
    int ty = ty0 * 4 + s;
    int mk = mk0 + tx, io = io0 + ty;
    int m = mk / 20, kx = mk % 20;
    const float* src = (m < 20) ? w1 : w2;
    int mm = (m < 20) ? m : (m - 20);
    size_t idx = ((((size_t)l * 4096 + io) * 20 + mm) * 20 + kx) * 2;
    tile[ty][tx] = make_float2(src[idx], src[idx + 1]);
  }
  __syncthreads();
  #pragma unroll
  for (int s = 0; s < 4; ++s) {
    int ty = ty0 * 4 + s;
    wT[(size_t)(mk0 + ty) * 4096 + (io0 + tx)] = tile[tx][ty];
  }
}

// ---------------------------------------------------------------------------
__global__ __launch_bounds__(256) void k_mix(const float2* __restrict__ Fxy,
                                             const float2* __restrict__ wT,
                                             float2* __restrict__ G, int nrows) {
  __shared__ float2 sf[512];
  int mk = blockIdx.x;
  for (int t = threadIdx.x; t < nrows; t += 256) sf[t] = Fxy[(size_t)t * 800 + mk];
  __syncthreads();
  const float2* wp = wT + (size_t)mk * 4096;
  for (int t = threadIdx.x; t < nrows; t += 256) {
    int b = t >> 6, o = t & 63;
    const float2* fb = sf + b * 64;
    float re = 0.f, im = 0.f;
    #pragma unroll 8
    for (int i = 0; i < 64; ++i) {
      float2 f = fb[i];
      float2 w = wp[i * 64 + o];
      re += f.x * w.x - f.y * w.y;
      im += f.x * w.y + f.y * w.x;
    }
    G[(size_t)(b * 64 + o) * 800 + mk] = make_float2(re, im);
  }
}

// ---------------------------------------------------------------------------
__global__ __launch_bounds__(256) void k_invy(const float2* __restrict__ G,
                                              const float2* __restrict__ Ty,
                                              float2* __restrict__ Gy) {
  int t  = blockIdx.x * 256 + threadIdx.x;   // cb*64*256*20
  int kx = t % 20;
  int y  = (t / 20) & 255;
  int bc = t / 5120;
  const float2* gp = G + (size_t)bc * 800 + kx;
  float re = 0.f, im = 0.f;
  #pragma unroll 4
  for (int m = 0; m < 40; ++m) {
    float2 g = gp[m * 20];
    float2 w = Ty[m * 256 + y];
    re += g.x * w.x - g.y * w.y;
    im += g.x * w.y + g.y * w.x;
  }
  Gy[t] = make_float2(re, im);
}

// ---------------------------------------------------------------------------
// MFMA 3x3 conv (implicit GEMM, split-f16 3-pass) + spectral add + gelu.
// Tile: 4 rows x 32 cols (M=128) x 64 outputs, NHWC. 18 K-chunks (tap,half).
__global__ __launch_bounds__(256, 3) void k_conv(const float* __restrict__ hin,
                                                 const f16x8* __restrict__ wph,
                                                 const f16x8* __restrict__ wpl,
                                                 const float* __restrict__ bcb,
                                                 const float2* __restrict__ Gy,
                                                 const float2* __restrict__ Tx,
                                                 float* __restrict__ hout,
                                                 int dogelu) {
  __shared__ unsigned sAu[13056];            // 52224 B; reused for Gy/Tx epilogue
  int bidx = blockIdx.x;
  int xt = bidx & 7;
  int yt = (bidx >> 3) & 63;
  int bb = bidx >> 9;
  int x0 = xt << 5, y0 = yt << 2;
  int tid = threadIdx.x;
  int w = tid >> 6, lane = tid & 63, quad = lane >> 4, l15 = lane & 15;

  // ---- stage activation tile (6x34 halo, 64 ch) as hi/lo f16, swizzled ----
  for (int e = tid; e < 204 * 32; e += 256) {
    int px = e >> 5, chp = e & 31;
    int rg = px / 34, cg = px % 34;
    int gy = y0 - 1 + rg, gx = x0 - 1 + cg;
    float2 v = make_float2(0.f, 0.f);
    if (gy >= 0 && gy < 256 && gx >= 0 && gx < 256)
      v = *(const float2*)(hin + (((size_t)bb * 256 + gy) * 256 + gx) * 64 + chp * 2);
    _Float16 h0 = (_Float16)v.x, h1 = (_Float16)v.y;
    _Float16 l0 = (_Float16)(v.x - (float)h0), l1 = (_Float16)(v.y - (float)h1);
    int dw = (px << 5) + (chp ^ ((px & 7) << 2));
    sAu[dw] = pack2(h0, h1);
    sAu[6528 + dw] = pack2(l0, l1);
  }
  __syncthreads();

  f32x4 acc[2][4];
  #pragma unroll
  for (int s = 0; s < 2; ++s)
    #pragma unroll
    for (int nt = 0; nt < 4; ++nt) acc[s][nt] = (f32x4){0.f, 0.f, 0.f, 0.f};

  // ---- main K loop ----
  #pragma unroll 1
  for (int tap = 0; tap < 9; ++tap) {
    int dy = tap / 3, dx = tap % 3;
    #pragma unroll
    for (int half = 0; half < 2; ++half) {
      int chunk = tap * 2 + half;
      const f16x8* bh = wph + (size_t)(chunk * 4) * 64 + lane;
      const f16x8* bl = wpl + (size_t)(chunk * 4) * 64 + lane;
      f16x8 bfh[4], bfl[4];
      #pragma unroll
      for (int nt = 0; nt < 4; ++nt) { bfh[nt] = bh[nt * 64]; bfl[nt] = bl[nt * 64]; }
      f16x8 afh[2], afl[2];
      #pragma unroll
      for (int s = 0; s < 2; ++s) {
        int px = (w + dy) * 34 + (s * 16 + dx) + l15;
        int dw = (px << 5) + (((half << 4) + (quad << 2)) ^ ((px & 7) << 2));
        afh[s] = *(const f16x8*)(sAu + dw);
        afl[s] = *(const f16x8*)(sAu + 6528 + dw);
      }
      #pragma unroll
      for (int s = 0; s < 2; ++s)
        #pragma unroll
        for (int nt = 0; nt < 4; ++nt) {
          acc[s][nt] = __builtin_amdgcn_mfma_f32_16x16x32_f16(afh[s], bfh[nt], acc[s][nt], 0, 0, 0);
          acc[s][nt] = __builtin_amdgcn_mfma_f32_16x16x32_f16(afh[s], bfl[nt], acc[s][nt], 0, 0, 0);
          acc[s][nt] = __builtin_amdgcn_mfma_f32_16x16x32_f16(afl[s], bfh[nt], acc[s][nt], 0, 0, 0);
        }
    }
  }

  // ---- epilogue: stage Gy tile + Tx cols in (reused) LDS ----
  __syncthreads();
  float2* sGy = (float2*)sAu;                 // [o*82 + row*20 + kx]
  float2* sT  = (float2*)(sAu + 10496);       // [kx*32 + col]
  for (int e = tid; e < 5120; e += 256) {
    int o = e / 80, rem = e % 80;
    int row = rem / 20, kx = rem % 20;
    sGy[o * 82 + row * 20 + kx] =
        Gy[((size_t)(bb * 64 + o) * 256 + (y0 + row)) * 20 + kx];
  }
  for (int e = tid; e < 640; e += 256) {
    int kx = e >> 5, col = e & 31;
    sT[e] = Tx[kx * 256 + x0 + col];
  }
  __syncthreads();

  const float scale = 1.f / 256.f;
  #pragma unroll
  for (int s = 0; s < 2; ++s) {
    int colb = s * 16 + (quad << 2);
    #pragma unroll
    for (int nt = 0; nt < 4; ++nt) {
      int o = nt * 16 + l15;
      float bias = bcb[o];
      const float2* gp = sGy + o * 82 + w * 20;
      f32x4 sr = {0.f, 0.f, 0.f, 0.f};
      #pragma unroll
      for (int p = 0; p < 10; ++p) {
        float4 g = *(const float4*)(gp + 2 * p);
        float f0 = (p == 0) ? 1.f : 2.f;
        float4 tA = *(const float4*)(sT + (2 * p) * 32 + colb);
        float4 tB = *(const float4*)(sT + (2 * p) * 32 + colb + 2);
        sr.x += f0 * (g.x * tA.x - g.y * tA.y);
        sr.y += f0 * (g.x * tA.z - g.y * tA.w);
        sr.z += f0 * (g.x * tB.x - g.y * tB.y);
        sr.w += f0 * (g.x * tB.z - g.y * tB.w);
        float4 tC = *(const float4*)(sT + (2 * p + 1) * 32 + colb);
        float4 tD = *(const float4*)(sT + (2 * p + 1) * 32 + colb + 2);
        sr.x += 2.f * (g.z * tC.x - g.w * tC.y);
        sr.y += 2.f * (g.z * tC.z - g.w * tC.w);
        sr.z += 2.f * (g.z * tD.x - g.w * tD.y);
        sr.w += 2.f * (g.z * tD.z - g.w * tD.w);
      }
      #pragma unroll
      for (int r = 0; r < 4; ++r) {
        float v = acc[s][nt][r] + bias + sr[r] * scale;
        if (dogelu) v = gelu_f(v);
        int xcol = x0 + colb + r;
        hout[(((size_t)bb * 256 + (y0 + w)) * 256 + xcol) * 64 + o] = v;
      }
    }
  }
}

// ---------------------------------------------------------------------------
// Head: MFMA fc1 (split-f16) + gelu + fc2 via shfl reduce. NHWC input.
__global__ __launch_bounds__(256, 2) void k_head(const float* __restrict__ h,
                                                 const f16x8* __restrict__ whi,
                                                 const f16x8* __restrict__ wlo,
                                                 const float* __restrict__ b1,
                                                 const float* __restrict__ w2,
                                                 const float* __restrict__ b2,
                                                 float* __restrict__ out, int b0) {
  int tid = threadIdx.x;
  int w = tid >> 6, lane = tid & 63, quad = lane >> 4, l15 = lane & 15;
  int px0 = blockIdx.x * 64 + w * 16;

  f32x4 acc[8];
  #pragma unroll
  for (int nt = 0; nt < 8; ++nt) acc[nt] = (f32x4){0.f, 0.f, 0.f, 0.f};

  #pragma unroll
  for (int half = 0; half < 2; ++half) {
    const float* ap = h + (size_t)(px0 + l15) * 64 + half * 32 + quad * 8;
    float4 a0 = *(const float4*)ap;
    float4 a1 = *(const float4*)(ap + 4);
    _Float16 ah[8], al[8];
    float av[8] = {a0.x, a0.y, a0.z, a0.w, a1.x, a1.y, a1.z, a1.w};
    #pragma unroll
    for (int j = 0; j < 8; ++j) {
      ah[j] = (_Float16)av[j];
      al[j] = (_Float16)(av[j] - (float)ah[j]);
    }
    f16x8 afh = *(f16x8*)ah, afl = *(f16x8*)al;
    #pragma unroll
    for (int nt = 0; nt < 8; ++nt) {
      f16x8 bh = whi[(size_t)(half * 8 + nt) * 64 + lane];
      f16x8 bl = wlo[(size_t)(half * 8 + nt) * 64 + lane];
      acc[nt] = __builtin_amdgcn_mfma_f32_16x16x32_f16(afh, bh, acc[nt], 0, 0, 0);
      acc[nt] = __builtin_amdgcn_mfma_f32_16x16x32_f16(afh, bl, acc[nt], 0, 0, 0);
      acc[nt] = __builtin_amdgcn_mfma_f32_16x16x32_f16(afl, bh, acc[nt], 0, 0, 0);
    }
  }

  float part[4] = {0.f, 0.f, 0.f, 0.f};
  #pragma unroll
  for (int nt = 0; nt < 8; ++nt) {
    int jo = nt * 16 + l15;
    float bb1 = b1[jo], ww2 = w2[jo];
    #pragma unroll
    for (int r = 0; r < 4; ++r)
      part[r] += gelu_f(acc[nt][r] + bb1) * ww2;
  }
  #pragma unroll
  for (int r = 0; r < 4; ++r) {
    float v = part[r];
    v += __shfl_xor(v, 1);
    v += __shfl_xor(v, 2);
    v += __shfl_xor(v, 4);
    v += __shfl_xor(v, 8);
    if (l15 == 0)
      out[(size_t)b0 * 65536 + px0 + quad * 4 + r] = v + b2[0];
  }
}

// ---------------------------------------------------------------------------
extern "C" void kernel_launch(void* const* d_in, const int* in_sizes, int n_in,
                              void* d_out, int out_size, void* d_ws, size_t ws_size,
                              hipStream_t stream) {
  const float* x    = (const float*)d_in[0];
  const float* fc0w = (const float*)d_in[1];
  const float* fc0b = (const float*)d_in[2];
  const float* w1   = (const float*)d_in[3];
  const float* w2   = (const float*)d_in[4];
  const float* chw  = (const float*)d_in[5];
  const float* chb  = (const float*)d_in[6];
  const float* cww  = (const float*)d_in[7];
  const float* cwb  = (const float*)d_in[8];
  const float* pww  = (const float*)d_in[9];
  const float* pwb  = (const float*)d_in[10];
  const float* fc1w = (const float*)d_in[11];
  const float* fc1b = (const float*)d_in[12];
  const float* fc2w = (const float*)d_in[13];
  const float* fc2b = (const float*)d_in[14];

  int cb = 1;
  for (int cand = 8; cand >= 1; cand >>= 1) {
    size_t need = (PERCB_FLOATS * (size_t)cand + FIXED_FLOATS) * sizeof(float);
    if (ws_size >= need) { cb = cand; break; }
  }

  const size_t szH = (size_t)cb * 4194304;

  float*  ws  = (float*)d_ws;
  float*  h   = ws;
  float*  h2  = h + szH;
  float2* Fx  = (float2*)(h2 + szH);
  float2* Fxy = (float2*)((float*)Fx + (size_t)cb * 655360);
  float2* G   = (float2*)((float*)Fxy + (size_t)cb * 102400);
  float2* wT  = (float2*)((float*)G + (size_t)cb * 102400);
  float2* Tx  = (float2*)((float*)wT + 6553600);
  float2* Ty  = (float2*)((float*)Tx + 10240);
  float*  wcb = (float*)Ty + 20480;
  float*  bcb = wcb + 147456;
  _Float16* wpkhi = (_Float16*)(bcb + 256);
  _Float16* wpklo = wpkhi + 147456;
  _Float16* w1hi  = wpklo + 147456;
  _Float16* w1lo  = w1hi + 8192;
  float2* Gy = Fx;   // Fx dead after k_fwdy

  k_tables<<<60, 256, 0, stream>>>(Tx, Ty);
  k_wc<<<576, 256, 0, stream>>>(chw, cww, pww, chb, cwb, pwb, wcb, bcb);
  k_wpack<<<72, 256, 0, stream>>>(wcb, wpkhi, wpklo);
  k_hpack<<<4, 256, 0, stream>>>(fc1w, w1hi, w1lo);

  for (int b0 = 0; b0 < NB; b0 += cb) {
    k_fc0<<<cb * 16384, 256, 0, stream>>>(x, fc0w, fc0b, h, b0);
    float* cur = h;
    float* nxt = h2;
    for (int l = 0; l < NL; ++l) {
      k_fwdx<<<cb * 256, 256, 0, stream>>>(cur, Tx, Fx);
      k_fwdy<<<cb * 200, 256, 0, stream>>>(Fx, Ty, Fxy);
      k_wT<<<dim3(25, 128), 256, 0, stream>>>(w1, w2, wT, l);
      k_mix<<<NM * NKX, 256, 0, stream>>>(Fxy, wT, G, cb * 64);
      k_invy<<<cb * 1280, 256, 0, stream>>>(G, Ty, Gy);
      k_conv<<<cb * 512, 256, 0, stream>>>(cur,
                                           (const f16x8*)(wpkhi + (size_t)l * 36864),
                                           (const f16x8*)(wpklo + (size_t)l * 36864),
                                           bcb + (size_t)l * 64, Gy, Tx, nxt,
                                           (l < NL - 1) ? 1 : 0);
      float* tmp = cur; cur = nxt; nxt = tmp;
    }
    k_head<<<cb * 1024, 256, 0, stream>>>(cur, (const f16x8*)w1hi, (const f16x8*)w1lo,
                                          fc1b, fc2w, fc2b, (float*)d_out, b0);
  }
}

// Round 7
// 4770.420 us; speedup vs baseline: 1.8215x; 1.0335x over previous
//
#include <hip/hip_runtime.h>
#include <math.h>

#define NB 8
#define NC 64
#define NH 256
#define NW 256
#define NM 40      // 2*MODES1
#define NKX 20     // MODES2
#define NL 4

typedef _Float16 f16x8 __attribute__((ext_vector_type(8)));
typedef float    f32x4 __attribute__((ext_vector_type(4)));

// ---- workspace (floats) ----
#define PERCB_FLOATS ((size_t)(2*4194304 + 655360 + 2*102400))   // 9,248,768
#define FIXED_FLOATS ((size_t)(6553600 + 10240 + 20480 + 147456 + 256 + 155648))

static __device__ __forceinline__ float gelu_f(float v) {
  return 0.5f * v * (1.f + erff(v * 0.70710678118654752f));
}
static __device__ __forceinline__ unsigned pack2(_Float16 a, _Float16 b) {
  union { _Float16 h[2]; unsigned u; } x; x.h[0] = a; x.h[1] = b; return x.u;
}

// ---------------------------------------------------------------------------
__global__ __launch_bounds__(256) void k_tables(float2* __restrict__ Tx,
                                                float2* __restrict__ Ty) {
  int t = blockIdx.x * 256 + threadIdx.x;
  const float w = (float)(2.0 * 3.14159265358979323846 / 256.0);
  if (t < NKX * 256) {
    int kx = t >> 8, x = t & 255;
    float th = (float)((kx * x) & 255) * w;
    Tx[t] = make_float2(cosf(th), sinf(th));
  }
  int u = t - NKX * 256;
  if (u >= 0 && u < NM * 256) {
    int m = u >> 8, y = u & 255;
    int ky = (m < 20) ? m : (m + 216);
    float th = (float)((ky * y) & 255) * w;
    Ty[u] = make_float2(cosf(th), sinf(th));
  }
}

// ---------------------------------------------------------------------------
__global__ __launch_bounds__(256) void k_wc(const float* __restrict__ ch,
                                            const float* __restrict__ cw,
                                            const float* __restrict__ pw,
                                            const float* __restrict__ chb,
                                            const float* __restrict__ cwb,
                                            const float* __restrict__ pwb,
                                            float* __restrict__ wc,
                                            float* __restrict__ bc) {
  int t = blockIdx.x * 256 + threadIdx.x;
  if (t < NL * NC * NC * 9) {
    int tap = t % 9;
    int io  = t / 9;
    int o   = io % 64;
    int i   = (io / 64) % 64;
    int l   = io / 4096;
    int src = ((l * 64 + o) * 64 + i) * 9 + tap;
    float v = ch[src] + cw[src];
    if (tap == 4) v += pw[(l * 64 + o) * 64 + i];
    wc[t] = v;
  }
  if (t < NL * NC) bc[t] = chb[t] + cwb[t] + pwb[t];
}

// ---------------------------------------------------------------------------
// Pack conv weights into MFMA b-frag order, split into f16 hi/lo.
__global__ __launch_bounds__(256) void k_wpack(const float* __restrict__ wc,
                                               _Float16* __restrict__ whi,
                                               _Float16* __restrict__ wlo) {
  int t = blockIdx.x * 256 + threadIdx.x;     // 4*18*4*64 = 18432
  int lane = t & 63;
  int nt   = (t >> 6) & 3;
  int chunk = (t >> 8) % 18;
  int l4   = t / 4608;
  int tap = chunk >> 1, half = chunk & 1;
  int o = nt * 16 + (lane & 15);
  _Float16 hi[8], lo[8];
  #pragma unroll
  for (int j = 0; j < 8; ++j) {
    int i = half * 32 + ((lane >> 4) << 3) + j;
    float v = wc[((l4 * 64 + i) * 64 + o) * 9 + tap];
    _Float16 h = (_Float16)v;
    hi[j] = h;
    lo[j] = (_Float16)(v - (float)h);
  }
  *(f16x8*)(whi + (size_t)t * 8) = *(f16x8*)hi;
  *(f16x8*)(wlo + (size_t)t * 8) = *(f16x8*)lo;
}

// ---------------------------------------------------------------------------
__global__ __launch_bounds__(256) void k_hpack(const float* __restrict__ w1,
                                               _Float16* __restrict__ whi,
                                               _Float16* __restrict__ wlo) {
  int t = blockIdx.x * 256 + threadIdx.x;     // 2*8*64 = 1024
  int lane = t & 63;
  int nt   = (t >> 6) & 7;
  int chunk = t >> 9;
  int jo = nt * 16 + (lane & 15);
  _Float16 hi[8], lo[8];
  #pragma unroll
  for (int j = 0; j < 8; ++j) {
    int c = chunk * 32 + ((lane >> 4) << 3) + j;
    float v = w1[c * 128 + jo];
    _Float16 h = (_Float16)v;
    hi[j] = h;
    lo[j] = (_Float16)(v - (float)h);
  }
  *(f16x8*)(whi + (size_t)t * 8) = *(f16x8*)hi;
  *(f16x8*)(wlo + (size_t)t * 8) = *(f16x8*)lo;
}

// ---------------------------------------------------------------------------
// fc0 lift -> h in NHWC: h[px*64 + ch]
__global__ __launch_bounds__(256) void k_fc0(const float* __restrict__ x,
                                             const float* __restrict__ w,
                                             const float* __restrict__ b,
                                             float* __restrict__ h, int b0) {
  int t = blockIdx.x * 256 + threadIdx.x;    // cb*65536*64
  int ch = t & 63;
  int px = t >> 6;
  const float* xp = x + ((size_t)b0 * 65536 + px) * 3;
  h[t] = xp[0] * w[ch] + xp[1] * w[64 + ch] + xp[2] * w[128 + ch] + b[ch];
}

// ---------------------------------------------------------------------------
// Forward x-DFT. Block = (bb,y). Stage the whole y-row (256x * 64ch fp32,
// 64 KB) in LDS once -> h read exactly once from HBM (was 4x: one per wave).
__global__ __launch_bounds__(256) void k_fwdx(const float* __restrict__ h,
                                              const float2* __restrict__ Tx,
                                              float2* __restrict__ Fx) {
  __shared__ float sm[16384];              // [x*64 + ch]
  int bidx = blockIdx.x;
  int y  = bidx & 255;
  int bb = bidx >> 8;
  const float* hp = h + ((size_t)bb * 65536 + y * 256) * 64;
  for (int e = threadIdx.x; e < 4096; e += 256)
    *(float4*)(sm + e * 4) = *(const float4*)(hp + e * 4);
  __syncthreads();
  int w  = threadIdx.x >> 6;
  int ch = threadIdx.x & 63;
  float ar[5] = {0,0,0,0,0}, ai[5] = {0,0,0,0,0};
  #pragma unroll 4
  for (int x = 0; x < 256; x += 2) {
    float v0 = sm[x * 64 + ch];
    float v1 = sm[x * 64 + 64 + ch];
    #pragma unroll
    for (int q = 0; q < 5; ++q) {
      int kx = w * 5 + q;
      float4 t4 = *(const float4*)(Tx + kx * 256 + x);
      ar[q] += v0 * t4.x + v1 * t4.z;
      ai[q] -= v0 * t4.y + v1 * t4.w;
    }
  }
  float2* fp = Fx + ((size_t)(bb * 64 + ch) * 256 + y) * 20;
  #pragma unroll
  for (int q = 0; q < 5; ++q) fp[w * 5 + q] = make_float2(ar[q], ai[q]);
}

// ---------------------------------------------------------------------------
// Forward y-DFT. One block per bc; Fx slice (40 KB) staged in LDS, read ONCE
// from HBM (was re-read 40x, once per m). Output transposed: FxyT[mk][bc]
// so k_mix's staging read is coalesced.
__global__ __launch_bounds__(256) void k_fwdy(const float2* __restrict__ Fx,
                                              const float2* __restrict__ Ty,
                                              float2* __restrict__ FxyT, int nbc) {
  __shared__ float2 sFx[5120];             // [y*20 + kx], 40 KB
  int bc = blockIdx.x;
  const float4* src = (const float4*)(Fx + (size_t)bc * 5120);
  float4* dst = (float4*)sFx;
  for (int e = threadIdx.x; e < 2560; e += 256) dst[e] = src[e];
  __syncthreads();
  for (int mk = threadIdx.x; mk < 800; mk += 256) {
    int kx = mk % 20, m = mk / 20;
    const float2* tp = Ty + m * 256;
    float re = 0.f, im = 0.f;
    #pragma unroll 4
    for (int yy = 0; yy < 256; ++yy) {
      float2 f = sFx[yy * 20 + kx];
      float2 wv = tp[yy];
      re += f.x * wv.x + f.y * wv.y;
      im += f.y * wv.x - f.x * wv.y;
    }
    FxyT[(size_t)mk * nbc + bc] = make_float2(re * (1.f / 256.f), im * (1.f / 256.f));
  }
}

// ---------------------------------------------------------------------------
__global__ __launch_bounds__(256) void k_wT(const float* __restrict__ w1,
                                            const float* __restrict__ w2,
                                            float2* __restrict__ wT, int l) {
  __shared__ float2 tile[32][33];
  int mk0 = blockIdx.x * 32;   // 25
  int io0 = blockIdx.y * 32;   // 128
  int tx = threadIdx.x & 31, ty0 = threadIdx.x >> 5;
  #pragma unroll
  for (int s = 0; s < 4; ++s) {
    int ty = ty0 * 4 + s;
    int mk = mk0 + tx, io = io0 + ty;
    int m = mk / 20, kx = mk % 20;
    const float* src = (m < 20) ? w1 : w2;
    int mm = (m < 20) ? m : (m - 20);
    size_t idx = ((((size_t)l * 4096 + io) * 20 + mm) * 20 + kx) * 2;
    tile[ty][tx] = make_float2(src[idx], src[idx + 1]);
  }
  __syncthreads();
  #pragma unroll
  for (int s = 0; s < 4; ++s) {
    int ty = ty0 * 4 + s;
    wT[(size_t)(mk0 + ty) * 4096 + (io0 + tx)] = tile[tx][ty];
  }
}

// ---------------------------------------------------------------------------
// Channel mix. Staging now reads FxyT[mk][0..nrows) contiguously (coalesced).
__global__ __launch_bounds__(256) void k_mix(const float2* __restrict__ FxyT,
                                             const float2* __restrict__ wT,
                                             float2* __restrict__ G, int nrows) {
  __shared__ float2 sf[512];
  int mk = blockIdx.x;
  for (int t = threadIdx.x; t < nrows; t += 256)
    sf[t] = FxyT[(size_t)mk * nrows + t];
  __syncthreads();
  const float2* wp = wT + (size_t)mk * 4096;
  for (int t = threadIdx.x; t < nrows; t += 256) {
    int b = t >> 6, o = t & 63;
    const float2* fb = sf + b * 64;
    float re = 0.f, im = 0.f;
    #pragma unroll 8
    for (int i = 0; i < 64; ++i) {
      float2 f = fb[i];
      float2 w = wp[i * 64 + o];
      re += f.x * w.x - f.y * w.y;
      im += f.x * w.y + f.y * w.x;
    }
    G[(size_t)(b * 64 + o) * 800 + mk] = make_float2(re, im);
  }
}

// ---------------------------------------------------------------------------
__global__ __launch_bounds__(256) void k_invy(const float2* __restrict__ G,
                                              const float2* __restrict__ Ty,
                                              float2* __restrict__ Gy) {
  int t  = blockIdx.x * 256 + threadIdx.x;   // cb*64*256*20
  int kx = t % 20;
  int y  = (t / 20) & 255;
  int bc = t / 5120;
  const float2* gp = G + (size_t)bc * 800 + kx;
  float re = 0.f, im = 0.f;
  #pragma unroll 4
  for (int m = 0; m < 40; ++m) {
    float2 g = gp[m * 20];
    float2 w = Ty[m * 256 + y];
    re += g.x * w.x - g.y * w.y;
    im += g.x * w.y + g.y * w.x;
  }
  Gy[t] = make_float2(re, im);
}

// ---------------------------------------------------------------------------
// MFMA 3x3 conv (implicit GEMM, split-f16 3-pass) + spectral add + gelu.
// Epilogue v2: accumulators transposed through LDS so each 128 B line of the
// NHWC output is written by contiguous dwordx4 stores (was 32 scattered
// scalar stores/thread -> 7x HBM write amplification).
__global__ __launch_bounds__(256, 3) void k_conv(const float* __restrict__ hin,
                                                 const f16x8* __restrict__ wph,
                                                 const f16x8* __restrict__ wpl,
                                                 const float* __restrict__ bcb,
                                                 const float2* __restrict__ Gy,
                                                 const float2* __restrict__ Tx,
                                                 float* __restrict__ hout,
                                                 int dogelu) {
  __shared__ unsigned sAu[13056];            // 52224 B; reused in epilogue
  int bidx = blockIdx.x;
  int xt = bidx & 7;
  int yt = (bidx >> 3) & 63;
  int bb = bidx >> 9;
  int x0 = xt << 5, y0 = yt << 2;
  int tid = threadIdx.x;
  int w = tid >> 6, lane = tid & 63, quad = lane >> 4, l15 = lane & 15;

  // ---- stage activation tile (6x34 halo, 64 ch) as hi/lo f16, swizzled ----
  for (int e = tid; e < 204 * 32; e += 256) {
    int px = e >> 5, chp = e & 31;
    int rg = px / 34, cg = px % 34;
    int gy = y0 - 1 + rg, gx = x0 - 1 + cg;
    float2 v = make_float2(0.f, 0.f);
    if (gy >= 0 && gy < 256 && gx >= 0 && gx < 256)
      v = *(const float2*)(hin + (((size_t)bb * 256 + gy) * 256 + gx) * 64 + chp * 2);
    _Float16 h0 = (_Float16)v.x, h1 = (_Float16)v.y;
    _Float16 l0 = (_Float16)(v.x - (float)h0), l1 = (_Float16)(v.y - (float)h1);
    int dw = (px << 5) + (chp ^ ((px & 7) << 2));
    sAu[dw] = pack2(h0, h1);
    sAu[6528 + dw] = pack2(l0, l1);
  }
  __syncthreads();

  f32x4 acc[2][4];
  #pragma unroll
  for (int s = 0; s < 2; ++s)
    #pragma unroll
    for (int nt = 0; nt < 4; ++nt) acc[s][nt] = (f32x4){0.f, 0.f, 0.f, 0.f};

  // ---- main K loop ----
  #pragma unroll 1
  for (int tap = 0; tap < 9; ++tap) {
    int dy = tap / 3, dx = tap % 3;
    #pragma unroll
    for (int half = 0; half < 2; ++half) {
      int chunk = tap * 2 + half;
      const f16x8* bh = wph + (size_t)(chunk * 4) * 64 + lane;
      const f16x8* bl = wpl + (size_t)(chunk * 4) * 64 + lane;
      f16x8 bfh[4], bfl[4];
      #pragma unroll
      for (int nt = 0; nt < 4; ++nt) { bfh[nt] = bh[nt * 64]; bfl[nt] = bl[nt * 64]; }
      f16x8 afh[2], afl[2];
      #pragma unroll
      for (int s = 0; s < 2; ++s) {
        int px = (w + dy) * 34 + (s * 16 + dx) + l15;
        int dw = (px << 5) + (((half << 4) + (quad << 2)) ^ ((px & 7) << 2));
        afh[s] = *(const f16x8*)(sAu + dw);
        afl[s] = *(const f16x8*)(sAu + 6528 + dw);
      }
      #pragma unroll
      for (int s = 0; s < 2; ++s)
        #pragma unroll
        for (int nt = 0; nt < 4; ++nt) {
          acc[s][nt] = __builtin_amdgcn_mfma_f32_16x16x32_f16(afh[s], bfh[nt], acc[s][nt], 0, 0, 0);
          acc[s][nt] = __builtin_amdgcn_mfma_f32_16x16x32_f16(afh[s], bfl[nt], acc[s][nt], 0, 0, 0);
          acc[s][nt] = __builtin_amdgcn_mfma_f32_16x16x32_f16(afl[s], bfh[nt], acc[s][nt], 0, 0, 0);
        }
    }
  }

  // ---- epilogue ----
  __syncthreads();
  float2* sT  = (float2*)sAu;              // 640 f2  = 5120 B   (u32 0..1280)
  float2* sGy = (float2*)(sAu + 1280);     // 32*82 f2 = 20992 B (u32 1280..6528)
  float*  sTr = (float*)(sAu + 6528);      // 128*36 f = 18432 B (u32 6528..11136)
  for (int e = tid; e < 640; e += 256) {
    int kx = e >> 5, col = e & 31;
    sT[e] = Tx[kx * 256 + x0 + col];
  }
  const float scale = 1.f / 256.f;
  #pragma unroll 1
  for (int oh = 0; oh < 2; ++oh) {
    __syncthreads();
    // stage Gy for o in [oh*32, oh*32+32)
    for (int e = tid; e < 2560; e += 256) {
      int ol = e / 80, rem = e % 80;
      int row = rem / 20, kx = rem % 20;
      sGy[ol * 82 + row * 20 + kx] =
          Gy[((size_t)(bb * 64 + oh * 32 + ol) * 256 + (y0 + row)) * 20 + kx];
    }
    __syncthreads();
    // compute spectral + bias + gelu, deposit transposed into sTr
    #pragma unroll
    for (int nt2 = 0; nt2 < 2; ++nt2) {
      int nt = oh * 2 + nt2;
      int ol = nt2 * 16 + l15;
      int o  = oh * 32 + ol;
      float bias = bcb[o];
      const float2* gp = sGy + ol * 82 + w * 20;
      #pragma unroll
      for (int s = 0; s < 2; ++s) {
        int colb = s * 16 + (quad << 2);
        f32x4 sr = {0.f, 0.f, 0.f, 0.f};
        #pragma unroll
        for (int p = 0; p < 10; ++p) {
          float4 g = *(const float4*)(gp + 2 * p);
          float f0 = (p == 0) ? 1.f : 2.f;
          float4 tA = *(const float4*)(sT + (2 * p) * 32 + colb);
          float4 tB = *(const float4*)(sT + (2 * p) * 32 + colb + 2);
          sr.x += f0 * (g.x * tA.x - g.y * tA.y);
          sr.y += f0 * (g.x * tA.z - g.y * tA.w);
          sr.z += f0 * (g.x * tB.x - g.y * tB.y);
          sr.w += f0 * (g.x * tB.z - g.y * tB.w);
          float4 tC = *(const float4*)(sT + (2 * p + 1) * 32 + colb);
          float4 tD = *(const float4*)(sT + (2 * p + 1) * 32 + colb + 2);
          sr.x += 2.f * (g.z * tC.x - g.w * tC.y);
          sr.y += 2.f * (g.z * tC.z - g.w * tC.w);
          sr.z += 2.f * (g.z * tD.x - g.w * tD.y);
          sr.w += 2.f * (g.z * tD.z - g.w * tD.w);
        }
        #pragma unroll
        for (int r = 0; r < 4; ++r) {
          float v = acc[s][nt][r] + bias + sr[r] * scale;
          if (dogelu) v = gelu_f(v);
          sTr[(w * 32 + s * 16 + (quad << 2) + r) * 36 + ol] = v;
        }
      }
    }
    __syncthreads();
    // write out: 128 px x 32 ch, dwordx4, 8 lanes cover one pixel's 128 B line
    #pragma unroll
    for (int k = 0; k < 4; ++k) {
      int e = tid + k * 256;              // [0,1024)
      int P = e >> 3, sub = e & 7;
      float4 v4 = *(const float4*)(sTr + P * 36 + sub * 4);
      int row = P >> 5, px32 = P & 31;
      *(float4*)(hout + (((size_t)bb * 256 + (y0 + row)) * 256 + x0 + px32) * 64
                 + oh * 32 + sub * 4) = v4;
    }
  }
}

// ---------------------------------------------------------------------------
// Head: MFMA fc1 (split-f16) + gelu + fc2 via shfl reduce. NHWC input.
__global__ __launch_bounds__(256, 2) void k_head(const float* __restrict__ h,
                                                 const f16x8* __restrict__ whi,
                                                 const f16x8* __restrict__ wlo,
                                                 const float* __restrict__ b1,
                                                 const float* __restrict__ w2,
                                                 const float* __restrict__ b2,
                                                 float* __restrict__ out, int b0) {
  int tid = threadIdx.x;
  int w = tid >> 6, lane = tid & 63, quad = lane >> 4, l15 = lane & 15;
  int px0 = blockIdx.x * 64 + w * 16;

  f32x4 acc[8];
  #pragma unroll
  for (int nt = 0; nt < 8; ++nt) acc[nt] = (f32x4){0.f, 0.f, 0.f, 0.f};

  #pragma unroll
  for (int half = 0; half < 2; ++half) {
    const float* ap = h + (size_t)(px0 + l15) * 64 + half * 32 + quad * 8;
    float4 a0 = *(const float4*)ap;
    float4 a1 = *(const float4*)(ap + 4);
    _Float16 ah[8], al[8];
    float av[8] = {a0.x, a0.y, a0.z, a0.w, a1.x, a1.y, a1.z, a1.w};
    #pragma unroll
    for (int j = 0; j < 8; ++j) {
      ah[j] = (_Float16)av[j];
      al[j] = (_Float16)(av[j] - (float)ah[j]);
    }
    f16x8 afh = *(f16x8*)ah, afl = *(f16x8*)al;
    #pragma unroll
    for (int nt = 0; nt < 8; ++nt) {
      f16x8 bh = whi[(size_t)(half * 8 + nt) * 64 + lane];
      f16x8 bl = wlo[(size_t)(half * 8 + nt) * 64 + lane];
      acc[nt] = __builtin_amdgcn_mfma_f32_16x16x32_f16(afh, bh, acc[nt], 0, 0, 0);
      acc[nt] = __builtin_amdgcn_mfma_f32_16x16x32_f16(afh, bl, acc[nt], 0, 0, 0);
      acc[nt] = __builtin_amdgcn_mfma_f32_16x16x32_f16(afl, bh, acc[nt], 0, 0, 0);
    }
  }

  float part[4] = {0.f, 0.f, 0.f, 0.f};
  #pragma unroll
  for (int nt = 0; nt < 8; ++nt) {
    int jo = nt * 16 + l15;
    float bb1 = b1[jo], ww2 = w2[jo];
    #pragma unroll
    for (int r = 0; r < 4; ++r)
      part[r] += gelu_f(acc[nt][r] + bb1) * ww2;
  }
  #pragma unroll
  for (int r = 0; r < 4; ++r) {
    float v = part[r];
    v += __shfl_xor(v, 1);
    v += __shfl_xor(v, 2);
    v += __shfl_xor(v, 4);
    v += __shfl_xor(v, 8);
    if (l15 == 0)
      out[(size_t)b0 * 65536 + px0 + quad * 4 + r] = v + b2[0];
  }
}

// ---------------------------------------------------------------------------
extern "C" void kernel_launch(void* const* d_in, const int* in_sizes, int n_in,
                              void* d_out, int out_size, void* d_ws, size_t ws_size,
                              hipStream_t stream) {
  const float* x    = (const float*)d_in[0];
  const float* fc0w = (const float*)d_in[1];
  const float* fc0b = (const float*)d_in[2];
  const float* w1   = (const float*)d_in[3];
  const float* w2   = (const float*)d_in[4];
  const float* chw  = (const float*)d_in[5];
  const float* chb  = (const float*)d_in[6];
  const float* cww  = (const float*)d_in[7];
  const float* cwb  = (const float*)d_in[8];
  const float* pww  = (const float*)d_in[9];
  const float* pwb  = (const float*)d_in[10];
  const float* fc1w = (const float*)d_in[11];
  const float* fc1b = (const float*)d_in[12];
  const float* fc2w = (const float*)d_in[13];
  const float* fc2b = (const float*)d_in[14];

  int cb = 1;
  for (int cand = 8; cand >= 1; cand >>= 1) {
    size_t need = (PERCB_FLOATS * (size_t)cand + FIXED_FLOATS) * sizeof(float);
    if (ws_size >= need) { cb = cand; break; }
  }

  const size_t szH = (size_t)cb * 4194304;

  float*  ws  = (float*)d_ws;
  float*  h   = ws;
  float*  h2  = h + szH;
  float2* Fx  = (float2*)(h2 + szH);
  float2* Fxy = (float2*)((float*)Fx + (size_t)cb * 655360);
  float2* G   = (float2*)((float*)Fxy + (size_t)cb * 102400);
  float2* wT  = (float2*)((float*)G + (size_t)cb * 102400);
  float2* Tx  = (float2*)((float*)wT + 6553600);
  float2* Ty  = (float2*)((float*)Tx + 10240);
  float*  wcb = (float*)Ty + 20480;
  float*  bcb = wcb + 147456;
  _Float16* wpkhi = (_Float16*)(bcb + 256);
  _Float16* wpklo = wpkhi + 147456;
  _Float16* w1hi  = wpklo + 147456;
  _Float16* w1lo  = w1hi + 8192;
  float2* Gy = Fx;   // Fx dead after k_fwdy

  k_tables<<<60, 256, 0, stream>>>(Tx, Ty);
  k_wc<<<576, 256, 0, stream>>>(chw, cww, pww, chb, cwb, pwb, wcb, bcb);
  k_wpack<<<72, 256, 0, stream>>>(wcb, wpkhi, wpklo);
  k_hpack<<<4, 256, 0, stream>>>(fc1w, w1hi, w1lo);

  for (int b0 = 0; b0 < NB; b0 += cb) {
    k_fc0<<<cb * 16384, 256, 0, stream>>>(x, fc0w, fc0b, h, b0);
    float* cur = h;
    float* nxt = h2;
    int nbc = cb * 64;
    for (int l = 0; l < NL; ++l) {
      k_fwdx<<<cb * 256, 256, 0, stream>>>(cur, Tx, Fx);
      k_fwdy<<<nbc, 256, 0, stream>>>(Fx, Ty, Fxy, nbc);
      k_wT<<<dim3(25, 128), 256, 0, stream>>>(w1, w2, wT, l);
      k_mix<<<NM * NKX, 256, 0, stream>>>(Fxy, wT, G, nbc);
      k_invy<<<cb * 1280, 256, 0, stream>>>(G, Ty, Gy);
      k_conv<<<cb * 512, 256, 0, stream>>>(cur,
                                           (const f16x8*)(wpkhi + (size_t)l * 36864),
                                           (const f16x8*)(wpklo + (size_t)l * 36864),
                                           bcb + (size_t)l * 64, Gy, Tx, nxt,
                                           (l < NL - 1) ? 1 : 0);
      float* tmp = cur; cur = nxt; nxt = tmp;
    }
    k_head<<<cb * 1024, 256, 0, stream>>>(cur, (const f16x8*)w1hi, (const f16x8*)w1lo,
                                          fc1b, fc2w, fc2b, (float*)d_out, b0);
  }
}

// Round 8
// 4373.584 us; speedup vs baseline: 1.9868x; 1.0907x over previous
//
#include <hip/hip_runtime.h>
#include <math.h>

#define NB 8
#define NC 64
#define NH 256
#define NW 256
#define NM 40      // 2*MODES1
#define NKX 20     // MODES2
#define NL 4

typedef _Float16 f16x8 __attribute__((ext_vector_type(8)));
typedef float    f32x4 __attribute__((ext_vector_type(4)));

// ---- workspace (floats) ----
#define PERCB_FLOATS ((size_t)(2*4194304 + 655360 + 2*102400))   // 9,248,768
#define FIXED_FLOATS ((size_t)(6553600 + 10240 + 20480 + 147456 + 256 + 167936 + 2048))

static __device__ __forceinline__ float gelu_f(float v) {
  return 0.5f * v * (1.f + erff(v * 0.70710678118654752f));
}
static __device__ __forceinline__ unsigned pack2(_Float16 a, _Float16 b) {
  union { _Float16 h[2]; unsigned u; } x; x.h[0] = a; x.h[1] = b; return x.u;
}

// ---------------------------------------------------------------------------
__global__ __launch_bounds__(256) void k_tables(float2* __restrict__ Tx,
                                                float2* __restrict__ Ty) {
  int t = blockIdx.x * 256 + threadIdx.x;
  const float w = (float)(2.0 * 3.14159265358979323846 / 256.0);
  if (t < NKX * 256) {
    int kx = t >> 8, x = t & 255;
    float th = (float)((kx * x) & 255) * w;
    Tx[t] = make_float2(cosf(th), sinf(th));
  }
  int u = t - NKX * 256;
  if (u >= 0 && u < NM * 256) {
    int m = u >> 8, y = u & 255;
    int ky = (m < 20) ? m : (m + 216);
    float th = (float)((ky * y) & 255) * w;
    Ty[u] = make_float2(cosf(th), sinf(th));
  }
}

// ---------------------------------------------------------------------------
// Pack forward-x twiddles into MFMA b-frag layout, split f16 hi/lo.
// B[k=x][n], n=2*kx+ri: re col = cos, im col = -sin. N padded 40->48.
// t = ((kc*3 + nt)*64 + lane)*8 + j
__global__ __launch_bounds__(256) void k_txpack(_Float16* __restrict__ th,
                                                _Float16* __restrict__ tl) {
  int t = blockIdx.x * 256 + threadIdx.x;   // 12288
  int j = t & 7, lane = (t >> 3) & 63;
  int rest = t >> 9;
  int nt = rest % 3, kc = rest / 3;
  int x = kc * 32 + ((lane >> 4) << 3) + j;
  int n = nt * 16 + (lane & 15);
  float val = 0.f;
  if (n < 40) {
    int kx = n >> 1;
    const float w = (float)(2.0 * 3.14159265358979323846 / 256.0);
    float ang = (float)((kx * x) & 255) * w;
    val = (n & 1) ? -sinf(ang) : cosf(ang);
  }
  _Float16 hi = (_Float16)val;
  th[t] = hi;
  tl[t] = (_Float16)(val - (float)hi);
}

// ---------------------------------------------------------------------------
__global__ __launch_bounds__(256) void k_wc(const float* __restrict__ ch,
                                            const float* __restrict__ cw,
                                            const float* __restrict__ pw,
                                            const float* __restrict__ chb,
                                            const float* __restrict__ cwb,
                                            const float* __restrict__ pwb,
                                            float* __restrict__ wc,
                                            float* __restrict__ bc) {
  int t = blockIdx.x * 256 + threadIdx.x;
  if (t < NL * NC * NC * 9) {
    int tap = t % 9;
    int io  = t / 9;
    int o   = io % 64;
    int i   = (io / 64) % 64;
    int l   = io / 4096;
    int src = ((l * 64 + o) * 64 + i) * 9 + tap;
    float v = ch[src] + cw[src];
    if (tap == 4) v += pw[(l * 64 + o) * 64 + i];
    wc[t] = v;
  }
  if (t < NL * NC) bc[t] = chb[t] + cwb[t] + pwb[t];
}

// ---------------------------------------------------------------------------
__global__ __launch_bounds__(256) void k_wpack(const float* __restrict__ wc,
                                               _Float16* __restrict__ whi,
                                               _Float16* __restrict__ wlo) {
  int t = blockIdx.x * 256 + threadIdx.x;     // 4*18*4*64 = 18432
  int lane = t & 63;
  int nt   = (t >> 6) & 3;
  int chunk = (t >> 8) % 18;
  int l4   = t / 4608;
  int tap = chunk >> 1, half = chunk & 1;
  int o = nt * 16 + (lane & 15);
  _Float16 hi[8], lo[8];
  #pragma unroll
  for (int j = 0; j < 8; ++j) {
    int i = half * 32 + ((lane >> 4) << 3) + j;
    float v = wc[((l4 * 64 + i) * 64 + o) * 9 + tap];
    _Float16 h = (_Float16)v;
    hi[j] = h;
    lo[j] = (_Float16)(v - (float)h);
  }
  *(f16x8*)(whi + (size_t)t * 8) = *(f16x8*)hi;
  *(f16x8*)(wlo + (size_t)t * 8) = *(f16x8*)lo;
}

// ---------------------------------------------------------------------------
__global__ __launch_bounds__(256) void k_hpack(const float* __restrict__ w1,
                                               _Float16* __restrict__ whi,
                                               _Float16* __restrict__ wlo) {
  int t = blockIdx.x * 256 + threadIdx.x;     // 2*8*64 = 1024
  int lane = t & 63;
  int nt   = (t >> 6) & 7;
  int chunk = t >> 9;
  int jo = nt * 16 + (lane & 15);
  _Float16 hi[8], lo[8];
  #pragma unroll
  for (int j = 0; j < 8; ++j) {
    int c = chunk * 32 + ((lane >> 4) << 3) + j;
    float v = w1[c * 128 + jo];
    _Float16 h = (_Float16)v;
    hi[j] = h;
    lo[j] = (_Float16)(v - (float)h);
  }
  *(f16x8*)(whi + (size_t)t * 8) = *(f16x8*)hi;
  *(f16x8*)(wlo + (size_t)t * 8) = *(f16x8*)lo;
}

// ---------------------------------------------------------------------------
// fc0 lift -> h in NHWC: h[px*64 + ch]
__global__ __launch_bounds__(256) void k_fc0(const float* __restrict__ x,
                                             const float* __restrict__ w,
                                             const float* __restrict__ b,
                                             float* __restrict__ h, int b0) {
  int t = blockIdx.x * 256 + threadIdx.x;    // cb*65536*64
  int ch = t & 63;
  int px = t >> 6;
  const float* xp = x + ((size_t)b0 * 65536 + px) * 3;
  h[t] = xp[0] * w[ch] + xp[1] * w[64 + ch] + xp[2] * w[128 + ch] + b[ch];
}

// ---------------------------------------------------------------------------
// Forward x-DFT as split-f16 MFMA GEMM. Block = (bb, y).
// C[c=64, n=48] = sum_x A[c,x] B[x,n];  A = h row (staged LDS, f16 hi/lo
// transposed to [ch][x]), B = prepacked twiddles. 2 K-stages of 128.
__global__ __launch_bounds__(256) void k_fwdx(const float* __restrict__ h,
                                              const f16x8* __restrict__ txh,
                                              const f16x8* __restrict__ txl,
                                              float2* __restrict__ Fx) {
  __shared__ _Float16 sH[64 * 136 * 2];    // hi [ch*136+xx], lo +8704
  int y = blockIdx.x & 255, bb = blockIdx.x >> 8;
  int tid = threadIdx.x;
  int w = tid >> 6, lane = tid & 63, quad = lane >> 4, l15 = lane & 15;
  const float* hp = h + ((size_t)(bb * 256 + y) * 256) * 64;

  f32x4 acc[3];
  #pragma unroll
  for (int nt = 0; nt < 3; ++nt) acc[nt] = (f32x4){0.f, 0.f, 0.f, 0.f};

  #pragma unroll 1
  for (int hs = 0; hs < 2; ++hs) {
    __syncthreads();
    #pragma unroll
    for (int it = 0; it < 8; ++it) {
      int e = it * 256 + tid;              // 2048
      int xx = e >> 4;                     // 0..127
      int chg = (e & 15) << 2;
      float4 v = *(const float4*)(hp + ((size_t)(hs * 128 + xx)) * 64 + chg);
      float vv[4] = {v.x, v.y, v.z, v.w};
      #pragma unroll
      for (int k = 0; k < 4; ++k) {
        _Float16 hi = (_Float16)vv[k];
        sH[(chg + k) * 136 + xx] = hi;
        sH[8704 + (chg + k) * 136 + xx] = (_Float16)(vv[k] - (float)hi);
      }
    }
    __syncthreads();
    #pragma unroll
    for (int kc = 0; kc < 4; ++kc) {
      int xb = kc * 32 + (quad << 3);
      f16x8 ah = *(const f16x8*)(sH + (w * 16 + l15) * 136 + xb);
      f16x8 al = *(const f16x8*)(sH + 8704 + (w * 16 + l15) * 136 + xb);
      int kcg = hs * 4 + kc;
      #pragma unroll
      for (int nt = 0; nt < 3; ++nt) {
        f16x8 bh = txh[(size_t)(kcg * 3 + nt) * 64 + lane];
        f16x8 bl = txl[(size_t)(kcg * 3 + nt) * 64 + lane];
        acc[nt] = __builtin_amdgcn_mfma_f32_16x16x32_f16(ah, bh, acc[nt], 0, 0, 0);
        acc[nt] = __builtin_amdgcn_mfma_f32_16x16x32_f16(ah, bl, acc[nt], 0, 0, 0);
        acc[nt] = __builtin_amdgcn_mfma_f32_16x16x32_f16(al, bh, acc[nt], 0, 0, 0);
      }
    }
  }
  // store: D row m = quad*4+r -> c = w*16+quad*4+r; col n = nt*16+l15
  #pragma unroll
  for (int nt = 0; nt < 3; ++nt) {
    int n = nt * 16 + l15;
    if (n < 40) {
      int kx = n >> 1, ri = n & 1;
      #pragma unroll
      for (int r = 0; r < 4; ++r) {
        int c = w * 16 + (quad << 2) + r;
        ((float*)(Fx + ((size_t)(bb * 64 + c) * 256 + y) * 20 + kx))[ri] = acc[nt][r];
      }
    }
  }
}

// ---------------------------------------------------------------------------
// Forward y-DFT. One block per bc; Fx slice (40 KB) in LDS, read once.
// Output transposed: FxyT[mk][bc].
__global__ __launch_bounds__(256) void k_fwdy(const float2* __restrict__ Fx,
                                              const float2* __restrict__ Ty,
                                              float2* __restrict__ FxyT, int nbc) {
  __shared__ float2 sFx[5120];
  int bc = blockIdx.x;
  const float4* src = (const float4*)(Fx + (size_t)bc * 5120);
  float4* dst = (float4*)sFx;
  for (int e = threadIdx.x; e < 2560; e += 256) dst[e] = src[e];
  __syncthreads();
  for (int mk = threadIdx.x; mk < 800; mk += 256) {
    int kx = mk % 20, m = mk / 20;
    const float2* tp = Ty + m * 256;
    float re = 0.f, im = 0.f;
    #pragma unroll 4
    for (int yy = 0; yy < 256; ++yy) {
      float2 f = sFx[yy * 20 + kx];
      float2 wv = tp[yy];
      re += f.x * wv.x + f.y * wv.y;
      im += f.y * wv.x - f.x * wv.y;
    }
    FxyT[(size_t)mk * nbc + bc] = make_float2(re * (1.f / 256.f), im * (1.f / 256.f));
  }
}

// ---------------------------------------------------------------------------
__global__ __launch_bounds__(256) void k_wT(const float* __restrict__ w1,
                                            const float* __restrict__ w2,
                                            float2* __restrict__ wT, int l) {
  __shared__ float2 tile[32][33];
  int mk0 = blockIdx.x * 32;   // 25
  int io0 = blockIdx.y * 32;   // 128
  int tx = threadIdx.x & 31, ty0 = threadIdx.x >> 5;
  #pragma unroll
  for (int s = 0; s < 4; ++s) {
    int ty = ty0 * 4 + s;
    int mk = mk0 + tx, io = io0 + ty;
    int m = mk / 20, kx = mk % 20;
    const float* src = (m < 20) ? w1 : w2;
    int mm = (m < 20) ? m : (m - 20);
    size_t idx = ((((size_t)l * 4096 + io) * 20 + mm) * 20 + kx) * 2;
    tile[ty][tx] = make_float2(src[idx], src[idx + 1]);
  }
  __syncthreads();
  #pragma unroll
  for (int s = 0; s < 4; ++s) {
    int ty = ty0 * 4 + s;
    wT[(size_t)(mk0 + ty) * 4096 + (io0 + tx)] = tile[tx][ty];
  }
}

// ---------------------------------------------------------------------------
__global__ __launch_bounds__(256) void k_mix(const float2* __restrict__ FxyT,
                                             const float2* __restrict__ wT,
                                             float2* __restrict__ G, int nrows) {
  __shared__ float2 sf[512];
  int mk = blockIdx.x;
  for (int t = threadIdx.x; t < nrows; t += 256)
    sf[t] = FxyT[(size_t)mk * nrows + t];
  __syncthreads();
  const float2* wp = wT + (size_t)mk * 4096;
  for (int t = threadIdx.x; t < nrows; t += 256) {
    int b = t >> 6, o = t & 63;
    const float2* fb = sf + b * 64;
    float re = 0.f, im = 0.f;
    #pragma unroll 8
    for (int i = 0; i < 64; ++i) {
      float2 f = fb[i];
      float2 w = wp[i * 64 + o];
      re += f.x * w.x - f.y * w.y;
      im += f.x * w.y + f.y * w.x;
    }
    G[(size_t)(b * 64 + o) * 800 + mk] = make_float2(re, im);
  }
}

// ---------------------------------------------------------------------------
__global__ __launch_bounds__(256) void k_invy(const float2* __restrict__ G,
                                              const float2* __restrict__ Ty,
                                              float2* __restrict__ Gy) {
  int t  = blockIdx.x * 256 + threadIdx.x;   // cb*64*256*20
  int kx = t % 20;
  int y  = (t / 20) & 255;
  int bc = t / 5120;
  const float2* gp = G + (size_t)bc * 800 + kx;
  float re = 0.f, im = 0.f;
  #pragma unroll 4
  for (int m = 0; m < 40; ++m) {
    float2 g = gp[m * 20];
    float2 w = Ty[m * 256 + y];
    re += g.x * w.x - g.y * w.y;
    im += g.x * w.y + g.y * w.x;
  }
  Gy[t] = make_float2(re, im);
}

// ---------------------------------------------------------------------------
// MFMA 3x3 conv + spectral add + gelu.
// Epilogue v3: full 64-o Gy staged at once (42 KB, fits since sTr removed);
// stores grouped nt-innermost so each 256 B pixel line is filled by 4
// back-to-back instructions (test of the partial-line write-amp theory).
__global__ __launch_bounds__(256, 3) void k_conv(const float* __restrict__ hin,
                                                 const f16x8* __restrict__ wph,
                                                 const f16x8* __restrict__ wpl,
                                                 const float* __restrict__ bcb,
                                                 const float2* __restrict__ Gy,
                                                 const float2* __restrict__ Tx,
                                                 float* __restrict__ hout,
                                                 int dogelu) {
  __shared__ unsigned sAu[13056];            // 52224 B; reused in epilogue
  int bidx = blockIdx.x;
  int xt = bidx & 7;
  int yt = (bidx >> 3) & 63;
  int bb = bidx >> 9;
  int x0 = xt << 5, y0 = yt << 2;
  int tid = threadIdx.x;
  int w = tid >> 6, lane = tid & 63, quad = lane >> 4, l15 = lane & 15;

  float bias[4];
  #pragma unroll
  for (int nt = 0; nt < 4; ++nt) bias[nt] = bcb[nt * 16 + l15];

  // ---- stage activation tile (6x34 halo, 64 ch) as hi/lo f16, swizzled ----
  for (int e = tid; e < 204 * 32; e += 256) {
    int px = e >> 5, chp = e & 31;
    int rg = px / 34, cg = px % 34;
    int gy = y0 - 1 + rg, gx = x0 - 1 + cg;
    float2 v = make_float2(0.f, 0.f);
    if (gy >= 0 && gy < 256 && gx >= 0 && gx < 256)
      v = *(const float2*)(hin + (((size_t)bb * 256 + gy) * 256 + gx) * 64 + chp * 2);
    _Float16 h0 = (_Float16)v.x, h1 = (_Float16)v.y;
    _Float16 l0 = (_Float16)(v.x - (float)h0), l1 = (_Float16)(v.y - (float)h1);
    int dw = (px << 5) + (chp ^ ((px & 7) << 2));
    sAu[dw] = pack2(h0, h1);
    sAu[6528 + dw] = pack2(l0, l1);
  }
  __syncthreads();

  f32x4 acc[2][4];
  #pragma unroll
  for (int s = 0; s < 2; ++s)
    #pragma unroll
    for (int nt = 0; nt < 4; ++nt) acc[s][nt] = (f32x4){0.f, 0.f, 0.f, 0.f};

  // ---- main K loop ----
  #pragma unroll 1
  for (int tap = 0; tap < 9; ++tap) {
    int dy = tap / 3, dx = tap % 3;
    #pragma unroll
    for (int half = 0; half < 2; ++half) {
      int chunk = tap * 2 + half;
      const f16x8* bh = wph + (size_t)(chunk * 4) * 64 + lane;
      const f16x8* bl = wpl + (size_t)(chunk * 4) * 64 + lane;
      f16x8 bfh[4], bfl[4];
      #pragma unroll
      for (int nt = 0; nt < 4; ++nt) { bfh[nt] = bh[nt * 64]; bfl[nt] = bl[nt * 64]; }
      f16x8 afh[2], afl[2];
      #pragma unroll
      for (int s = 0; s < 2; ++s) {
        int px = (w + dy) * 34 + (s * 16 + dx) + l15;
        int dw = (px << 5) + (((half << 4) + (quad << 2)) ^ ((px & 7) << 2));
        afh[s] = *(const f16x8*)(sAu + dw);
        afl[s] = *(const f16x8*)(sAu + 6528 + dw);
      }
      #pragma unroll
      for (int s = 0; s < 2; ++s)
        #pragma unroll
        for (int nt = 0; nt < 4; ++nt) {
          acc[s][nt] = __builtin_amdgcn_mfma_f32_16x16x32_f16(afh[s], bfh[nt], acc[s][nt], 0, 0, 0);
          acc[s][nt] = __builtin_amdgcn_mfma_f32_16x16x32_f16(afh[s], bfl[nt], acc[s][nt], 0, 0, 0);
          acc[s][nt] = __builtin_amdgcn_mfma_f32_16x16x32_f16(afl[s], bfh[nt], acc[s][nt], 0, 0, 0);
        }
    }
  }

  // ---- epilogue ----
  __syncthreads();
  float2* sT  = (float2*)sAu;              // 640 f2  = 5120 B
  float2* sGy = (float2*)(sAu + 1280);     // 64*82 f2 = 41984 B; total 47104 B
  for (int e = tid; e < 640; e += 256) {
    int kx = e >> 5, col = e & 31;
    sT[e] = Tx[kx * 256 + x0 + col];
  }
  for (int e = tid; e < 5120; e += 256) {
    int o = e / 80, rem = e % 80;
    int row = rem / 20, kx = rem % 20;
    sGy[o * 82 + row * 20 + kx] =
        Gy[((size_t)(bb * 64 + o) * 256 + (y0 + row)) * 20 + kx];
  }
  __syncthreads();

  const float scale = 1.f / 256.f;
  #pragma unroll
  for (int s = 0; s < 2; ++s) {
    int colb = s * 16 + (quad << 2);
    float vv[4][4];                        // [nt][r]
    #pragma unroll
    for (int nt = 0; nt < 4; ++nt) {
      int o = nt * 16 + l15;
      const float2* gp = sGy + o * 82 + w * 20;
      f32x4 sr = {0.f, 0.f, 0.f, 0.f};
      #pragma unroll
      for (int p = 0; p < 10; ++p) {
        float4 g = *(const float4*)(gp + 2 * p);
        float f0 = (p == 0) ? 1.f : 2.f;
        float4 tA = *(const float4*)(sT + (2 * p) * 32 + colb);
        float4 tB = *(const float4*)(sT + (2 * p) * 32 + colb + 2);
        sr.x += f0 * (g.x * tA.x - g.y * tA.y);
        sr.y += f0 * (g.x * tA.z - g.y * tA.w);
        sr.z += f0 * (g.x * tB.x - g.y * tB.y);
        sr.w += f0 * (g.x * tB.z - g.y * tB.w);
        float4 tC = *(const float4*)(sT + (2 * p + 1) * 32 + colb);
        float4 tD = *(const float4*)(sT + (2 * p + 1) * 32 + colb + 2);
        sr.x += 2.f * (g.z * tC.x - g.w * tC.y);
        sr.y += 2.f * (g.z * tC.z - g.w * tC.w);
        sr.z += 2.f * (g.z * tD.x - g.w * tD.y);
        sr.w += 2.f * (g.z * tD.z - g.w * tD.w);
      }
      #pragma unroll
      for (int r = 0; r < 4; ++r) {
        float v = acc[s][nt][r] + bias[nt] + sr[r] * scale;
        if (dogelu) v = gelu_f(v);
        vv[nt][r] = v;
      }
    }
    // stores: nt innermost -> 4 consecutive instrs fill each 256 B line
    #pragma unroll
    for (int r = 0; r < 4; ++r) {
      size_t base = (((size_t)bb * 256 + (y0 + w)) * 256 + x0 + colb + r) * 64;
      #pragma unroll
      for (int nt = 0; nt < 4; ++nt)
        hout[base + nt * 16 + l15] = vv[nt][r];
    }
  }
}

// ---------------------------------------------------------------------------
// Head: MFMA fc1 (split-f16) + gelu + fc2 via shfl reduce. NHWC input.
__global__ __launch_bounds__(256, 2) void k_head(const float* __restrict__ h,
                                                 const f16x8* __restrict__ whi,
                                                 const f16x8* __restrict__ wlo,
                                                 const float* __restrict__ b1,
                                                 const float* __restrict__ w2,
                                                 const float* __restrict__ b2,
                                                 float* __restrict__ out, int b0) {
  int tid = threadIdx.x;
  int w = tid >> 6, lane = tid & 63, quad = lane >> 4, l15 = lane & 15;
  int px0 = blockIdx.x * 64 + w * 16;

  f32x4 acc[8];
  #pragma unroll
  for (int nt = 0; nt < 8; ++nt) acc[nt] = (f32x4){0.f, 0.f, 0.f, 0.f};

  #pragma unroll
  for (int half = 0; half < 2; ++half) {
    const float* ap = h + (size_t)(px0 + l15) * 64 + half * 32 + quad * 8;
    float4 a0 = *(const float4*)ap;
    float4 a1 = *(const float4*)(ap + 4);
    _Float16 ah[8], al[8];
    float av[8] = {a0.x, a0.y, a0.z, a0.w, a1.x, a1.y, a1.z, a1.w};
    #pragma unroll
    for (int j = 0; j < 8; ++j) {
      ah[j] = (_Float16)av[j];
      al[j] = (_Float16)(av[j] - (float)ah[j]);
    }
    f16x8 afh = *(f16x8*)ah, afl = *(f16x8*)al;
    #pragma unroll
    for (int nt = 0; nt < 8; ++nt) {
      f16x8 bh = whi[(size_t)(half * 8 + nt) * 64 + lane];
      f16x8 bl = wlo[(size_t)(half * 8 + nt) * 64 + lane];
      acc[nt] = __builtin_amdgcn_mfma_f32_16x16x32_f16(afh, bh, acc[nt], 0, 0, 0);
      acc[nt] = __builtin_amdgcn_mfma_f32_16x16x32_f16(afh, bl, acc[nt], 0, 0, 0);
      acc[nt] = __builtin_amdgcn_mfma_f32_16x16x32_f16(afl, bh, acc[nt], 0, 0, 0);
    }
  }

  float part[4] = {0.f, 0.f, 0.f, 0.f};
  #pragma unroll
  for (int nt = 0; nt < 8; ++nt) {
    int jo = nt * 16 + l15;
    float bb1 = b1[jo], ww2 = w2[jo];
    #pragma unroll
    for (int r = 0; r < 4; ++r)
      part[r] += gelu_f(acc[nt][r] + bb1) * ww2;
  }
  #pragma unroll
  for (int r = 0; r < 4; ++r) {
    float v = part[r];
    v += __shfl_xor(v, 1);
    v += __shfl_xor(v, 2);
    v += __shfl_xor(v, 4);
    v += __shfl_xor(v, 8);
    if (l15 == 0)
      out[(size_t)b0 * 65536 + px0 + quad * 4 + r] = v + b2[0];
  }
}

// ---------------------------------------------------------------------------
extern "C" void kernel_launch(void* const* d_in, const int* in_sizes, int n_in,
                              void* d_out, int out_size, void* d_ws, size_t ws_size,
                              hipStream_t stream) {
  const float* x    = (const float*)d_in[0];
  const float* fc0w = (const float*)d_in[1];
  const float* fc0b = (const float*)d_in[2];
  const float* w1   = (const float*)d_in[3];
  const float* w2   = (const float*)d_in[4];
  const float* chw  = (const float*)d_in[5];
  const float* chb  = (const float*)d_in[6];
  const float* cww  = (const float*)d_in[7];
  const float* cwb  = (const float*)d_in[8];
  const float* pww  = (const float*)d_in[9];
  const float* pwb  = (const float*)d_in[10];
  const float* fc1w = (const float*)d_in[11];
  const float* fc1b = (const float*)d_in[12];
  const float* fc2w = (const float*)d_in[13];
  const float* fc2b = (const float*)d_in[14];

  int cb = 1;
  for (int cand = 8; cand >= 1; cand >>= 1) {
    size_t need = (PERCB_FLOATS * (size_t)cand + FIXED_FLOATS) * sizeof(float);
    if (ws_size >= need) { cb = cand; break; }
  }

  const size_t szH = (size_t)cb * 4194304;

  float*  ws  = (float*)d_ws;
  float*  h   = ws;
  float*  h2  = h + szH;
  float2* Fx  = (float2*)(h2 + szH);
  float2* Fxy = (float2*)((float*)Fx + (size_t)cb * 655360);
  float2* G   = (float2*)((float*)Fxy + (size_t)cb * 102400);
  float2* wT  = (float2*)((float*)G + (size_t)cb * 102400);
  float2* Tx  = (float2*)((float*)wT + 6553600);
  float2* Ty  = (float2*)((float*)Tx + 10240);
  float*  wcb = (float*)Ty + 20480;
  float*  bcb = wcb + 147456;
  _Float16* wpkhi = (_Float16*)(bcb + 256);
  _Float16* wpklo = wpkhi + 147456;
  _Float16* w1hi  = wpklo + 147456;
  _Float16* w1lo  = w1hi + 8192;
  _Float16* txph  = w1lo + 8192;
  _Float16* txpl  = txph + 12288;
  float2* Gy = Fx;   // Fx dead after k_fwdy

  k_tables<<<60, 256, 0, stream>>>(Tx, Ty);
  k_txpack<<<48, 256, 0, stream>>>(txph, txpl);
  k_wc<<<576, 256, 0, stream>>>(chw, cww, pww, chb, cwb, pwb, wcb, bcb);
  k_wpack<<<72, 256, 0, stream>>>(wcb, wpkhi, wpklo);
  k_hpack<<<4, 256, 0, stream>>>(fc1w, w1hi, w1lo);

  for (int b0 = 0; b0 < NB; b0 += cb) {
    k_fc0<<<cb * 16384, 256, 0, stream>>>(x, fc0w, fc0b, h, b0);
    float* cur = h;
    float* nxt = h2;
    int nbc = cb * 64;
    for (int l = 0; l < NL; ++l) {
      k_fwdx<<<cb * 256, 256, 0, stream>>>(cur, (const f16x8*)txph,
                                           (const f16x8*)txpl, Fx);
      k_fwdy<<<nbc, 256, 0, stream>>>(Fx, Ty, Fxy, nbc);
      k_wT<<<dim3(25, 128), 256, 0, stream>>>(w1, w2, wT, l);
      k_mix<<<NM * NKX, 256, 0, stream>>>(Fxy, wT, G, nbc);
      k_invy<<<cb * 1280, 256, 0, stream>>>(G, Ty, Gy);
      k_conv<<<cb * 512, 256, 0, stream>>>(cur,
                                           (const f16x8*)(wpkhi + (size_t)l * 36864),
                                           (const f16x8*)(wpklo + (size_t)l * 36864),
                                           bcb + (size_t)l * 64, Gy, Tx, nxt,
                                           (l < NL - 1) ? 1 : 0);
      float* tmp = cur; cur = nxt; nxt = tmp;
    }
    k_head<<<cb * 1024, 256, 0, stream>>>(cur, (const f16x8*)w1hi, (const f16x8*)w1lo,
                                          fc1b, fc2w, fc2b, (float*)d_out, b0);
  }
}